// Round 6
// baseline (230.349 us; speedup 1.0000x reference)
//
#include <hip/hip_runtime.h>
#include <hip/hip_bf16.h>

// Problem: B=2, LQ=2048, LK=4096, D_MODEL=512, NHEAD=8, D_HEAD=64
// Inputs fp32 (+ int32 mask). Internal: bf16 MFMA, fp32 accumulation.
// Round 6: register-prefetch pipelines (attn K/V tiles, proj W phase-1),
// exp2 softmax path (gate pre-log2'd), Pt stride 68 (conflict-free P writes),
// bf16 K-split partials, prep/cvt fused to one launch. 5 dispatches total.

using bf16  = __hip_bfloat16;
using bf16x8 = __attribute__((ext_vector_type(8))) short;  // 8 bf16 = 4 VGPRs
using f32x4  = __attribute__((ext_vector_type(4))) float;

#define MFMA16(a, b, c) __builtin_amdgcn_mfma_f32_16x16x32_bf16((a), (b), (c), 0, 0, 0)

// 0.125 * log2(e): folds the 1/sqrt(64) scale and the exp->exp2 conversion
#define SCALE_LOG2E 0.18033688011112042f

__device__ __forceinline__ bf16x8 load8(const bf16* p) {
    return *reinterpret_cast<const bf16x8*>(p);
}
__device__ __forceinline__ short f2bf(float x) {
    bf16 h = __float2bfloat16(x);
    return *reinterpret_cast<short*>(&h);
}
__device__ __forceinline__ float bfb2f(short s) {
    unsigned int u = ((unsigned int)(unsigned short)s) << 16;
    return __builtin_bit_cast(float, u);
}

// ---------------------------------------------------------------------------
// One fused prep launch, 7200 blocks:
//   blocks 0..6143   : fp32->bf16 cvt of q (1/3) and kv (2/3), 4 elems/thread
//   blocks 6144..7167: fp32->bf16 cvt of the 4 weight matrices
//   blocks 7168..7199: gate -> g2 = mask ? log2(max(gate,1e-6)) : -1e30
// ---------------------------------------------------------------------------
__global__ void prep_all(const float* __restrict__ q, const float* __restrict__ kv,
                         const float* __restrict__ Wq, const float* __restrict__ Wk,
                         const float* __restrict__ Wv, const float* __restrict__ Wo,
                         const float* __restrict__ gate, const int* __restrict__ mask,
                         bf16* __restrict__ qb, bf16* __restrict__ kvb,
                         bf16* __restrict__ Wqb, bf16* __restrict__ Wkb,
                         bf16* __restrict__ Wvb, bf16* __restrict__ Wob,
                         float* __restrict__ g2) {
    const int bid = blockIdx.x;
    const int tid = threadIdx.x;
    if (bid < 7168) {
        const float* src; bf16* dst; int j;
        if (bid < 6144) {
            int i = bid * 256 + tid;                  // 0..1572863
            if (i < 524288) { src = q;  dst = qb;  j = i; }
            else            { src = kv; dst = kvb; j = i - 524288; }
        } else {
            int i = (bid - 6144) * 256 + tid;         // 0..262143
            int t = i >> 16; j = i & 65535;
            src = (t == 0) ? Wq : (t == 1) ? Wk : (t == 2) ? Wv : Wo;
            dst = (t == 0) ? Wqb : (t == 1) ? Wkb : (t == 2) ? Wvb : Wob;
        }
        float4 v = reinterpret_cast<const float4*>(src)[j];
        ushort4 o;
        o.x = (unsigned short)f2bf(v.x);
        o.y = (unsigned short)f2bf(v.y);
        o.z = (unsigned short)f2bf(v.z);
        o.w = (unsigned short)f2bf(v.w);
        reinterpret_cast<ushort4*>(dst)[j] = o;
    } else {
        int i = (bid - 7168) * 256 + tid;             // 0..8191
        float gv = fmaxf(gate[i], 1e-6f);
        g2[i] = mask[i] ? log2f(gv) : -1e30f;
    }
}

// ---------------------------------------------------------------------------
// Projection body: C = X @ W^T + bias. X:[M,512] bf16, W bf16 row-major
// W[out][in]. Block 256 thr / 4 waves; tile 128 rows x 64 cols; wave 32x64.
// W col-block in LDS, two 256-wide K phases (stride 264, bank-clean); the
// phase-1 W block is prefetched into registers during phase-0 compute.
// mode 0: fp32 row-major [M,512]
// mode 1: bf16 per-head   [(b*8+h)*L + i]*64 + dh
// mode 2: bf16 per-head^T [(b*8+h)*64 + dh]*L + i
// ---------------------------------------------------------------------------
__device__ __forceinline__ void proj_body(const bf16* __restrict__ X,
                                          const bf16* __restrict__ W,
                                          const float* __restrict__ bias,
                                          void* __restrict__ Cout,
                                          int mode, int L, int mb, bf16* Ws) {
    const int tid  = threadIdx.x;
    const int wave = tid >> 6;
    const int lane = tid & 63;
    const int li   = lane & 15;
    const int quad = lane >> 4;
    const int n0   = blockIdx.x * 64;
    const int m0   = mb * 128 + wave * 32;

    f32x4 zero = {0.f, 0.f, 0.f, 0.f};
    f32x4 acc[2][4];
    for (int mt = 0; mt < 2; ++mt)
        for (int t = 0; t < 4; ++t) acc[mt][t] = zero;

    const bf16* x0 = X + (size_t)(m0 + li) * 512;
    const bf16* x1 = X + (size_t)(m0 + 16 + li) * 512;

    // stage phase-0 W block
    for (int i = 0; i < 8; ++i) {
        const int c  = i * 256 + tid;
        const int cr = c >> 5;
        const int kc = (c & 31) * 8;
        *reinterpret_cast<bf16x8*>(&Ws[cr * 264 + kc]) =
            load8(W + (size_t)(n0 + cr) * 512 + kc);
    }
    __syncthreads();

    // prefetch phase-1 W block into regs
    bf16x8 wpre[8];
    for (int i = 0; i < 8; ++i) {
        const int c  = i * 256 + tid;
        const int cr = c >> 5;
        const int kc = (c & 31) * 8;
        wpre[i] = load8(W + (size_t)(n0 + cr) * 512 + 256 + kc);
    }

    // phase-0 compute
    for (int k0 = 0; k0 < 256; k0 += 32) {
        bf16x8 a0 = load8(x0 + k0 + quad * 8);
        bf16x8 a1 = load8(x1 + k0 + quad * 8);
        for (int t = 0; t < 4; ++t) {
            bf16x8 w8 = load8(&Ws[(t * 16 + li) * 264 + k0 + quad * 8]);
            acc[0][t] = MFMA16(a0, w8, acc[0][t]);
            acc[1][t] = MFMA16(a1, w8, acc[1][t]);
        }
    }
    __syncthreads();

    // write prefetched W, then phase-1 compute
    for (int i = 0; i < 8; ++i) {
        const int c  = i * 256 + tid;
        const int cr = c >> 5;
        const int kc = (c & 31) * 8;
        *reinterpret_cast<bf16x8*>(&Ws[cr * 264 + kc]) = wpre[i];
    }
    __syncthreads();

    for (int k0 = 0; k0 < 256; k0 += 32) {
        bf16x8 a0 = load8(x0 + 256 + k0 + quad * 8);
        bf16x8 a1 = load8(x1 + 256 + k0 + quad * 8);
        for (int t = 0; t < 4; ++t) {
            bf16x8 w8 = load8(&Ws[(t * 16 + li) * 264 + k0 + quad * 8]);
            acc[0][t] = MFMA16(a0, w8, acc[0][t]);
            acc[1][t] = MFMA16(a1, w8, acc[1][t]);
        }
    }

    for (int t = 0; t < 4; ++t) {
        const int col = n0 + t * 16 + li;
        const float bcol = bias[col];
        for (int mt = 0; mt < 2; ++mt) {
            for (int r = 0; r < 4; ++r) {
                const int row = m0 + mt * 16 + quad * 4 + r;   // C-layout
                const float v = acc[mt][t][r] + bcol;
                if (mode == 0) {
                    ((float*)Cout)[(size_t)row * 512 + col] = v;
                } else {
                    const int bb2 = row / L;
                    const int i   = row - bb2 * L;
                    const int hh  = col >> 6;
                    const int dh  = col & 63;
                    size_t idx;
                    if (mode == 1) idx = ((size_t)(bb2 * 8 + hh) * L + i) * 64 + dh;
                    else           idx = ((size_t)(bb2 * 8 + hh) * 64 + dh) * L + i;
                    ((bf16*)Cout)[idx] = __float2bfloat16(v);
                }
            }
        }
    }
}

// Fused Q/K/V projections: grid (8, 160). y<32: Q; y<96: K; else V.
__global__ void proj_qkv(const bf16* __restrict__ qb, const bf16* __restrict__ kvb,
                         const bf16* __restrict__ Wq, const float* __restrict__ bq,
                         const bf16* __restrict__ Wk, const float* __restrict__ bk,
                         const bf16* __restrict__ Wv, const float* __restrict__ bv,
                         bf16* __restrict__ qp, bf16* __restrict__ kp,
                         bf16* __restrict__ vpt) {
    __shared__ alignas(16) bf16 Ws[64 * 264];
    const int my = blockIdx.y;
    if (my < 32)      proj_body(qb,  Wq, bq, qp,  1, 2048, my,      Ws);
    else if (my < 96) proj_body(kvb, Wk, bk, kp,  1, 4096, my - 32, Ws);
    else              proj_body(kvb, Wv, bv, vpt, 2, 4096, my - 96, Ws);
}

// Output projection: grid (8, 32), fp32 out.
__global__ void proj_o(const bf16* __restrict__ op, const bf16* __restrict__ Wo,
                       const float* __restrict__ bo, float* __restrict__ out) {
    __shared__ alignas(16) bf16 Ws[64 * 264];
    proj_body(op, Wo, bo, out, 0, 1, blockIdx.y, Ws);
}

// ---------------------------------------------------------------------------
// K-split flash attention, no max-subtraction, exp2 path, reg-prefetch
// pipeline on K/V staging. Grid: 1024 = b(2) x h(8) x qtile(16) x ks(4).
// Block: 256 thr = 4 waves; wave owns 32 Q-rows. Writes UNNORMALIZED bf16
// partial O + fp32 l.
// ---------------------------------------------------------------------------
#define PS  72   // K/V tile stride
#define PTS 68   // P tile stride: quad rows land on banks 0/8/16/24 -> b16
                 // writes conflict-free (2 lanes/bank)
__global__ void attn_kernel(const bf16* __restrict__ qp, const bf16* __restrict__ kp,
                            const bf16* __restrict__ vpt, const float* __restrict__ g2,
                            bf16* __restrict__ Opart, float* __restrict__ lpart) {
    __shared__ alignas(16) bf16 Kt[64 * PS];
    __shared__ alignas(16) bf16 Vt[64 * PS];
    __shared__ alignas(16) bf16 Pt[4 * 32 * PTS];
    __shared__ float gs[64];

    const int tid  = threadIdx.x;
    const int wave = tid >> 6;
    const int lane = tid & 63;
    const int li   = lane & 15;
    const int quad = lane >> 4;

    const int bx = blockIdx.x;          // b*512 + h*64 + qt*4 + ks
    const int ks = bx & 3;
    const int qt = (bx >> 2) & 15;
    const int h  = (bx >> 6) & 7;
    const int b  = bx >> 9;
    const size_t bh = (size_t)(b * 8 + h);

    // Q fragments: 2 m-subtiles x 2 k-halves
    const bf16* qb0 = qp + (bh * 2048 + (size_t)qt * 128 + wave * 32 + li) * 64;
    bf16x8 aq[2][2];
    aq[0][0] = load8(qb0 + quad * 8);
    aq[0][1] = load8(qb0 + 32 + quad * 8);
    aq[1][0] = load8(qb0 + 16 * 64 + quad * 8);
    aq[1][1] = load8(qb0 + 16 * 64 + 32 + quad * 8);

    f32x4 zero = {0.f, 0.f, 0.f, 0.f};
    f32x4 o[2][4];
    for (int mt = 0; mt < 2; ++mt)
        for (int t = 0; t < 4; ++t) o[mt][t] = zero;
    float lsum[2][4] = {{0.f, 0.f, 0.f, 0.f}, {0.f, 0.f, 0.f, 0.f}};

    const bf16* ksrc  = kp  + bh * 4096 * 64;
    const bf16* vsrc  = vpt + bh * 64 * 4096;
    const float* gsrc = g2 + (size_t)b * 4096;

    bf16* PtW = &Pt[wave * 32 * PTS];
    const int r0 = tid >> 3;
    const int cg = (tid & 7) * 8;

    // prefetch first tile into regs
    bf16x8 pk0, pk1, pv0, pv1;
    float  pg = 0.f;
    {
        const bf16* kst = ksrc + (size_t)(ks * 16) * 4096;
        pk0 = load8(kst + r0 * 64 + cg);
        pk1 = load8(kst + (r0 + 32) * 64 + cg);
        const bf16* vs = vsrc + (ks * 16) * 64;
        pv0 = load8(vs + (size_t)r0 * 4096 + cg);
        pv1 = load8(vs + (size_t)(r0 + 32) * 4096 + cg);
        if (tid < 64) pg = gsrc[ks * 16 * 64 + tid];
    }

    for (int i = 0; i < 16; ++i) {
        // write staged regs to LDS
        *reinterpret_cast<bf16x8*>(&Kt[r0 * PS + cg])        = pk0;
        *reinterpret_cast<bf16x8*>(&Kt[(r0 + 32) * PS + cg]) = pk1;
        *reinterpret_cast<bf16x8*>(&Vt[r0 * PS + cg])        = pv0;
        *reinterpret_cast<bf16x8*>(&Vt[(r0 + 32) * PS + cg]) = pv1;
        if (tid < 64) gs[tid] = pg;
        __syncthreads();

        // prefetch next tile (global latency overlaps compute below)
        if (i < 15) {
            const int kt = ks * 16 + i + 1;
            const bf16* kst = ksrc + (size_t)kt * 4096;
            pk0 = load8(kst + r0 * 64 + cg);
            pk1 = load8(kst + (r0 + 32) * 64 + cg);
            const bf16* vs = vsrc + kt * 64;
            pv0 = load8(vs + (size_t)r0 * 4096 + cg);
            pv1 = load8(vs + (size_t)(r0 + 32) * 4096 + cg);
            if (tid < 64) pg = gsrc[kt * 64 + tid];
        }

        // S (32 x 64) = Q @ K_tile^T, then P = exp2(S*SCALE_LOG2E + g2)
        for (int t = 0; t < 4; ++t) {
            bf16x8 bk0 = load8(&Kt[(t * 16 + li) * PS + quad * 8]);
            bf16x8 bk1 = load8(&Kt[(t * 16 + li) * PS + 32 + quad * 8]);
            const float gv = gs[t * 16 + li];
            for (int mt = 0; mt < 2; ++mt) {
                f32x4 acc = zero;
                acc = MFMA16(aq[mt][0], bk0, acc);
                acc = MFMA16(aq[mt][1], bk1, acc);
                for (int r = 0; r < 4; ++r) {
                    const float p = exp2f(fmaf(acc[r], SCALE_LOG2E, gv));
                    lsum[mt][r] += p;
                    PtW[(mt * 16 + quad * 4 + r) * PTS + t * 16 + li] = __float2bfloat16(p);
                }
            }
        }

        // O += P @ V_tile
        bf16x8 ap[2][2];
        ap[0][0] = load8(&PtW[li * PTS + quad * 8]);
        ap[0][1] = load8(&PtW[li * PTS + 32 + quad * 8]);
        ap[1][0] = load8(&PtW[(16 + li) * PTS + quad * 8]);
        ap[1][1] = load8(&PtW[(16 + li) * PTS + 32 + quad * 8]);
        for (int t = 0; t < 4; ++t) {
            bf16x8 bv0 = load8(&Vt[(t * 16 + li) * PS + quad * 8]);
            bf16x8 bv1 = load8(&Vt[(t * 16 + li) * PS + 32 + quad * 8]);
            for (int mt = 0; mt < 2; ++mt) {
                o[mt][t] = MFMA16(ap[mt][0], bv0, o[mt][t]);
                o[mt][t] = MFMA16(ap[mt][1], bv1, o[mt][t]);
            }
        }
        __syncthreads();
    }

    // reduce l across the 16 lanes of each row group
    for (int off = 1; off < 16; off <<= 1)
        for (int mt = 0; mt < 2; ++mt)
            for (int r = 0; r < 4; ++r)
                lsum[mt][r] += __shfl_xor(lsum[mt][r], off);

    // write bf16 partial O (unnormalized) + fp32 l
    bf16* ob = Opart + ((size_t)bx * 128 + wave * 32) * 64;
    for (int mt = 0; mt < 2; ++mt)
        for (int t = 0; t < 4; ++t)
            for (int r = 0; r < 4; ++r)
                ob[(size_t)(mt * 16 + quad * 4 + r) * 64 + t * 16 + li] =
                    __float2bfloat16(o[mt][t][r]);
    if (li == 0)
        for (int mt = 0; mt < 2; ++mt)
            for (int r = 0; r < 4; ++r)
                lpart[(size_t)bx * 128 + wave * 32 + mt * 16 + quad * 4 + r] = lsum[mt][r];
}

// ---------------------------------------------------------------------------
// Combine 4 K-split partials (plain sums). Grid 512 x 256 thr.
// ---------------------------------------------------------------------------
__global__ void attn_combine(const bf16* __restrict__ Opart,
                             const float* __restrict__ lpart,
                             bf16* __restrict__ op) {
    const int gidx = blockIdx.x * 256 + threadIdx.x;  // 0..131071
    const int row  = gidx >> 2;                        // 0..32767 = (b,h,q)
    const int c0   = (gidx & 3) * 16;
    const int b    = row >> 14;
    const int h    = (row >> 11) & 7;
    const int q    = row & 2047;
    const int qt   = q >> 7;
    const int r128 = q & 127;
    const int base = (((b * 8 + h) * 16) + qt) * 4;

    float acc[16];
    for (int j = 0; j < 16; ++j) acc[j] = 0.f;
    float L = 0.f;
    for (int s = 0; s < 4; ++s) {
        const bf16* src = Opart + ((size_t)(base + s) * 128 + r128) * 64 + c0;
        bf16x8 v0 = load8(src);
        bf16x8 v1 = load8(src + 8);
        for (int j = 0; j < 8; ++j) {
            acc[j]     += bfb2f(v0[j]);
            acc[8 + j] += bfb2f(v1[j]);
        }
        L += lpart[(size_t)(base + s) * 128 + r128];
    }
    const float invL = 1.0f / L;

    bf16* dst = op + ((size_t)b * 2048 + q) * 512 + h * 64 + c0;
    bf16x8 o0, o1;
    for (int j = 0; j < 8; ++j) {
        o0[j] = f2bf(acc[j] * invL);
        o1[j] = f2bf(acc[8 + j] * invL);
    }
    *reinterpret_cast<bf16x8*>(dst)     = o0;
    *reinterpret_cast<bf16x8*>(dst + 8) = o1;
}

// ---------------------------------------------------------------------------
extern "C" void kernel_launch(void* const* d_in, const int* in_sizes, int n_in,
                              void* d_out, int out_size, void* d_ws, size_t ws_size,
                              hipStream_t stream) {
    const float* q    = (const float*)d_in[0];
    const float* kv   = (const float*)d_in[1];
    const float* gate = (const float*)d_in[2];
    const int*   mask = (const int*)d_in[3];
    const float* Wq = (const float*)d_in[4];  const float* bq = (const float*)d_in[5];
    const float* Wk = (const float*)d_in[6];  const float* bk = (const float*)d_in[7];
    const float* Wv = (const float*)d_in[8];  const float* bv = (const float*)d_in[9];
    const float* Wo = (const float*)d_in[10]; const float* bo = (const float*)d_in[11];
    float* out = (float*)d_out;

    // workspace (MB offsets): g2@0, Wqb@1, Wkb@1.5, Wvb@2, Wob@2.5, qb@3(4),
    // kvb@7(8), qp@15(4), kp@19(8), vpt@27(8), op@35(4),
    // Opart bf16 @39(16), lpart fp32 @55(0.5)  -> ~56 MB
    char* ws = (char*)d_ws;
    float* g2  = (float*)ws;
    bf16* Wqb  = (bf16*)(ws + (1u  << 20));
    bf16* Wkb  = (bf16*)(ws + (1u  << 20) + (512u << 10));
    bf16* Wvb  = (bf16*)(ws + (2u  << 20));
    bf16* Wob  = (bf16*)(ws + (2u  << 20) + (512u << 10));
    bf16* qb   = (bf16*)(ws + (3u  << 20));
    bf16* kvb  = (bf16*)(ws + (7u  << 20));
    bf16* qp   = (bf16*)(ws + (15u << 20));
    bf16* kp   = (bf16*)(ws + (19u << 20));
    bf16* vpt  = (bf16*)(ws + (27u << 20));
    bf16* op   = (bf16*)(ws + (35u << 20));
    bf16* Opart = (bf16*)(ws + (39u << 20));
    float* lpart = (float*)(ws + (55u << 20));

    prep_all<<<7200, 256, 0, stream>>>(q, kv, Wq, Wk, Wv, Wo, gate, mask,
                                       qb, kvb, Wqb, Wkb, Wvb, Wob, g2);
    proj_qkv<<<dim3(8, 160), 256, 0, stream>>>(qb, kvb, Wqb, bq, Wkb, bk,
                                               Wvb, bv, qp, kp, vpt);
    attn_kernel<<<1024, 256, 0, stream>>>(qp, kp, vpt, g2, Opart, lpart);
    attn_combine<<<512, 256, 0, stream>>>(Opart, lpart, op);
    proj_o<<<dim3(8, 32), 256, 0, stream>>>(op, Wob, bo, out);
}

// Round 7
// 226.408 us; speedup vs baseline: 1.0174x; 1.0174x over previous
//
#include <hip/hip_runtime.h>
#include <hip/hip_bf16.h>

// Problem: B=2, LQ=2048, LK=4096, D_MODEL=512, NHEAD=8, D_HEAD=64
// Inputs fp32 (+ int32 mask). Internal: bf16 MFMA, fp32 accumulation.
// Round 7: round-6 structure + __launch_bounds__(256,4) on the MFMA kernels.
// R6 regressed because the default 64-VGPR budget forced the compiler to
// sink/spill the prefetch pipeline; (256,4) raises the cap to 128 VGPRs
// (4 waves/EU = 4 blocks/CU, which LDS limits us to anyway).

using bf16  = __hip_bfloat16;
using bf16x8 = __attribute__((ext_vector_type(8))) short;  // 8 bf16 = 4 VGPRs
using f32x4  = __attribute__((ext_vector_type(4))) float;

#define MFMA16(a, b, c) __builtin_amdgcn_mfma_f32_16x16x32_bf16((a), (b), (c), 0, 0, 0)

// 0.125 * log2(e): folds the 1/sqrt(64) scale and the exp->exp2 conversion
#define SCALE_LOG2E 0.18033688011112042f

__device__ __forceinline__ bf16x8 load8(const bf16* p) {
    return *reinterpret_cast<const bf16x8*>(p);
}
__device__ __forceinline__ short f2bf(float x) {
    bf16 h = __float2bfloat16(x);
    return *reinterpret_cast<short*>(&h);
}
__device__ __forceinline__ float bfb2f(short s) {
    unsigned int u = ((unsigned int)(unsigned short)s) << 16;
    return __builtin_bit_cast(float, u);
}

// ---------------------------------------------------------------------------
// One fused prep launch, 7200 blocks:
//   blocks 0..6143   : fp32->bf16 cvt of q (1/3) and kv (2/3), 4 elems/thread
//   blocks 6144..7167: fp32->bf16 cvt of the 4 weight matrices
//   blocks 7168..7199: gate -> g2 = mask ? log2(max(gate,1e-6)) : -1e30
// ---------------------------------------------------------------------------
__global__ void prep_all(const float* __restrict__ q, const float* __restrict__ kv,
                         const float* __restrict__ Wq, const float* __restrict__ Wk,
                         const float* __restrict__ Wv, const float* __restrict__ Wo,
                         const float* __restrict__ gate, const int* __restrict__ mask,
                         bf16* __restrict__ qb, bf16* __restrict__ kvb,
                         bf16* __restrict__ Wqb, bf16* __restrict__ Wkb,
                         bf16* __restrict__ Wvb, bf16* __restrict__ Wob,
                         float* __restrict__ g2) {
    const int bid = blockIdx.x;
    const int tid = threadIdx.x;
    if (bid < 7168) {
        const float* src; bf16* dst; int j;
        if (bid < 6144) {
            int i = bid * 256 + tid;                  // 0..1572863
            if (i < 524288) { src = q;  dst = qb;  j = i; }
            else            { src = kv; dst = kvb; j = i - 524288; }
        } else {
            int i = (bid - 6144) * 256 + tid;         // 0..262143
            int t = i >> 16; j = i & 65535;
            src = (t == 0) ? Wq : (t == 1) ? Wk : (t == 2) ? Wv : Wo;
            dst = (t == 0) ? Wqb : (t == 1) ? Wkb : (t == 2) ? Wvb : Wob;
        }
        float4 v = reinterpret_cast<const float4*>(src)[j];
        ushort4 o;
        o.x = (unsigned short)f2bf(v.x);
        o.y = (unsigned short)f2bf(v.y);
        o.z = (unsigned short)f2bf(v.z);
        o.w = (unsigned short)f2bf(v.w);
        reinterpret_cast<ushort4*>(dst)[j] = o;
    } else {
        int i = (bid - 7168) * 256 + tid;             // 0..8191
        float gv = fmaxf(gate[i], 1e-6f);
        g2[i] = mask[i] ? log2f(gv) : -1e30f;
    }
}

// ---------------------------------------------------------------------------
// Projection body: C = X @ W^T + bias. X:[M,512] bf16, W bf16 row-major
// W[out][in]. Block 256 thr / 4 waves; tile 128 rows x 64 cols; wave 32x64.
// W col-block in LDS, two 256-wide K phases (stride 264, bank-clean); the
// phase-1 W block is prefetched into registers during phase-0 compute.
// mode 0: fp32 row-major [M,512]
// mode 1: bf16 per-head   [(b*8+h)*L + i]*64 + dh
// mode 2: bf16 per-head^T [(b*8+h)*64 + dh]*L + i
// ---------------------------------------------------------------------------
__device__ __forceinline__ void proj_body(const bf16* __restrict__ X,
                                          const bf16* __restrict__ W,
                                          const float* __restrict__ bias,
                                          void* __restrict__ Cout,
                                          int mode, int L, int mb, bf16* Ws) {
    const int tid  = threadIdx.x;
    const int wave = tid >> 6;
    const int lane = tid & 63;
    const int li   = lane & 15;
    const int quad = lane >> 4;
    const int n0   = blockIdx.x * 64;
    const int m0   = mb * 128 + wave * 32;

    f32x4 zero = {0.f, 0.f, 0.f, 0.f};
    f32x4 acc[2][4];
    for (int mt = 0; mt < 2; ++mt)
        for (int t = 0; t < 4; ++t) acc[mt][t] = zero;

    const bf16* x0 = X + (size_t)(m0 + li) * 512;
    const bf16* x1 = X + (size_t)(m0 + 16 + li) * 512;

    // stage phase-0 W block
    for (int i = 0; i < 8; ++i) {
        const int c  = i * 256 + tid;
        const int cr = c >> 5;
        const int kc = (c & 31) * 8;
        *reinterpret_cast<bf16x8*>(&Ws[cr * 264 + kc]) =
            load8(W + (size_t)(n0 + cr) * 512 + kc);
    }
    __syncthreads();

    // prefetch phase-1 W block into regs
    bf16x8 wpre[8];
    for (int i = 0; i < 8; ++i) {
        const int c  = i * 256 + tid;
        const int cr = c >> 5;
        const int kc = (c & 31) * 8;
        wpre[i] = load8(W + (size_t)(n0 + cr) * 512 + 256 + kc);
    }

    // phase-0 compute
    for (int k0 = 0; k0 < 256; k0 += 32) {
        bf16x8 a0 = load8(x0 + k0 + quad * 8);
        bf16x8 a1 = load8(x1 + k0 + quad * 8);
        for (int t = 0; t < 4; ++t) {
            bf16x8 w8 = load8(&Ws[(t * 16 + li) * 264 + k0 + quad * 8]);
            acc[0][t] = MFMA16(a0, w8, acc[0][t]);
            acc[1][t] = MFMA16(a1, w8, acc[1][t]);
        }
    }
    __syncthreads();

    // write prefetched W, then phase-1 compute
    for (int i = 0; i < 8; ++i) {
        const int c  = i * 256 + tid;
        const int cr = c >> 5;
        const int kc = (c & 31) * 8;
        *reinterpret_cast<bf16x8*>(&Ws[cr * 264 + kc]) = wpre[i];
    }
    __syncthreads();

    for (int k0 = 0; k0 < 256; k0 += 32) {
        bf16x8 a0 = load8(x0 + 256 + k0 + quad * 8);
        bf16x8 a1 = load8(x1 + 256 + k0 + quad * 8);
        for (int t = 0; t < 4; ++t) {
            bf16x8 w8 = load8(&Ws[(t * 16 + li) * 264 + k0 + quad * 8]);
            acc[0][t] = MFMA16(a0, w8, acc[0][t]);
            acc[1][t] = MFMA16(a1, w8, acc[1][t]);
        }
    }

    for (int t = 0; t < 4; ++t) {
        const int col = n0 + t * 16 + li;
        const float bcol = bias[col];
        for (int mt = 0; mt < 2; ++mt) {
            for (int r = 0; r < 4; ++r) {
                const int row = m0 + mt * 16 + quad * 4 + r;   // C-layout
                const float v = acc[mt][t][r] + bcol;
                if (mode == 0) {
                    ((float*)Cout)[(size_t)row * 512 + col] = v;
                } else {
                    const int bb2 = row / L;
                    const int i   = row - bb2 * L;
                    const int hh  = col >> 6;
                    const int dh  = col & 63;
                    size_t idx;
                    if (mode == 1) idx = ((size_t)(bb2 * 8 + hh) * L + i) * 64 + dh;
                    else           idx = ((size_t)(bb2 * 8 + hh) * 64 + dh) * L + i;
                    ((bf16*)Cout)[idx] = __float2bfloat16(v);
                }
            }
        }
    }
}

// Fused Q/K/V projections: grid (8, 160). y<32: Q; y<96: K; else V.
__global__ void __launch_bounds__(256, 4)
proj_qkv(const bf16* __restrict__ qb, const bf16* __restrict__ kvb,
         const bf16* __restrict__ Wq, const float* __restrict__ bq,
         const bf16* __restrict__ Wk, const float* __restrict__ bk,
         const bf16* __restrict__ Wv, const float* __restrict__ bv,
         bf16* __restrict__ qp, bf16* __restrict__ kp,
         bf16* __restrict__ vpt) {
    __shared__ alignas(16) bf16 Ws[64 * 264];
    const int my = blockIdx.y;
    if (my < 32)      proj_body(qb,  Wq, bq, qp,  1, 2048, my,      Ws);
    else if (my < 96) proj_body(kvb, Wk, bk, kp,  1, 4096, my - 32, Ws);
    else              proj_body(kvb, Wv, bv, vpt, 2, 4096, my - 96, Ws);
}

// Output projection: grid (8, 32), fp32 out.
__global__ void __launch_bounds__(256, 4)
proj_o(const bf16* __restrict__ op, const bf16* __restrict__ Wo,
       const float* __restrict__ bo, float* __restrict__ out) {
    __shared__ alignas(16) bf16 Ws[64 * 264];
    proj_body(op, Wo, bo, out, 0, 1, blockIdx.y, Ws);
}

// ---------------------------------------------------------------------------
// K-split flash attention, no max-subtraction, exp2 path, reg-prefetch
// pipeline on K/V staging. Grid: 1024 = b(2) x h(8) x qtile(16) x ks(4).
// Block: 256 thr = 4 waves; wave owns 32 Q-rows. Writes UNNORMALIZED bf16
// partial O + fp32 l.  __launch_bounds__(256,4): 128-VGPR budget so the
// prefetch regs stay resident (r6 at default 64 VGPR sank the pipeline).
// ---------------------------------------------------------------------------
#define PS  72   // K/V tile stride
#define PTS 68   // P tile stride
__global__ void __launch_bounds__(256, 4)
attn_kernel(const bf16* __restrict__ qp, const bf16* __restrict__ kp,
            const bf16* __restrict__ vpt, const float* __restrict__ g2,
            bf16* __restrict__ Opart, float* __restrict__ lpart) {
    __shared__ alignas(16) bf16 Kt[64 * PS];
    __shared__ alignas(16) bf16 Vt[64 * PS];
    __shared__ alignas(16) bf16 Pt[4 * 32 * PTS];
    __shared__ float gs[64];

    const int tid  = threadIdx.x;
    const int wave = tid >> 6;
    const int lane = tid & 63;
    const int li   = lane & 15;
    const int quad = lane >> 4;

    const int bx = blockIdx.x;          // b*512 + h*64 + qt*4 + ks
    const int ks = bx & 3;
    const int qt = (bx >> 2) & 15;
    const int h  = (bx >> 6) & 7;
    const int b  = bx >> 9;
    const size_t bh = (size_t)(b * 8 + h);

    // Q fragments: 2 m-subtiles x 2 k-halves
    const bf16* qb0 = qp + (bh * 2048 + (size_t)qt * 128 + wave * 32 + li) * 64;
    bf16x8 aq[2][2];
    aq[0][0] = load8(qb0 + quad * 8);
    aq[0][1] = load8(qb0 + 32 + quad * 8);
    aq[1][0] = load8(qb0 + 16 * 64 + quad * 8);
    aq[1][1] = load8(qb0 + 16 * 64 + 32 + quad * 8);

    f32x4 zero = {0.f, 0.f, 0.f, 0.f};
    f32x4 o[2][4];
    for (int mt = 0; mt < 2; ++mt)
        for (int t = 0; t < 4; ++t) o[mt][t] = zero;
    float lsum[2][4] = {{0.f, 0.f, 0.f, 0.f}, {0.f, 0.f, 0.f, 0.f}};

    const bf16* ksrc  = kp  + bh * 4096 * 64;
    const bf16* vsrc  = vpt + bh * 64 * 4096;
    const float* gsrc = g2 + (size_t)b * 4096;

    bf16* PtW = &Pt[wave * 32 * PTS];
    const int r0 = tid >> 3;
    const int cg = (tid & 7) * 8;

    // prefetch first tile into regs
    bf16x8 pk0, pk1, pv0, pv1;
    float  pg = 0.f;
    {
        const bf16* kst = ksrc + (size_t)(ks * 16) * 4096;
        pk0 = load8(kst + r0 * 64 + cg);
        pk1 = load8(kst + (r0 + 32) * 64 + cg);
        const bf16* vs = vsrc + (ks * 16) * 64;
        pv0 = load8(vs + (size_t)r0 * 4096 + cg);
        pv1 = load8(vs + (size_t)(r0 + 32) * 4096 + cg);
        if (tid < 64) pg = gsrc[ks * 16 * 64 + tid];
    }

    for (int i = 0; i < 16; ++i) {
        // write staged regs to LDS
        *reinterpret_cast<bf16x8*>(&Kt[r0 * PS + cg])        = pk0;
        *reinterpret_cast<bf16x8*>(&Kt[(r0 + 32) * PS + cg]) = pk1;
        *reinterpret_cast<bf16x8*>(&Vt[r0 * PS + cg])        = pv0;
        *reinterpret_cast<bf16x8*>(&Vt[(r0 + 32) * PS + cg]) = pv1;
        if (tid < 64) gs[tid] = pg;
        __syncthreads();

        // prefetch next tile (global latency overlaps compute below)
        if (i < 15) {
            const int kt = ks * 16 + i + 1;
            const bf16* kst = ksrc + (size_t)kt * 4096;
            pk0 = load8(kst + r0 * 64 + cg);
            pk1 = load8(kst + (r0 + 32) * 64 + cg);
            const bf16* vs = vsrc + kt * 64;
            pv0 = load8(vs + (size_t)r0 * 4096 + cg);
            pv1 = load8(vs + (size_t)(r0 + 32) * 4096 + cg);
            if (tid < 64) pg = gsrc[kt * 64 + tid];
        }

        // S (32 x 64) = Q @ K_tile^T, then P = exp2(S*SCALE_LOG2E + g2)
        for (int t = 0; t < 4; ++t) {
            bf16x8 bk0 = load8(&Kt[(t * 16 + li) * PS + quad * 8]);
            bf16x8 bk1 = load8(&Kt[(t * 16 + li) * PS + 32 + quad * 8]);
            const float gv = gs[t * 16 + li];
            for (int mt = 0; mt < 2; ++mt) {
                f32x4 acc = zero;
                acc = MFMA16(aq[mt][0], bk0, acc);
                acc = MFMA16(aq[mt][1], bk1, acc);
                for (int r = 0; r < 4; ++r) {
                    const float p = exp2f(fmaf(acc[r], SCALE_LOG2E, gv));
                    lsum[mt][r] += p;
                    PtW[(mt * 16 + quad * 4 + r) * PTS + t * 16 + li] = __float2bfloat16(p);
                }
            }
        }

        // O += P @ V_tile
        bf16x8 ap[2][2];
        ap[0][0] = load8(&PtW[li * PTS + quad * 8]);
        ap[0][1] = load8(&PtW[li * PTS + 32 + quad * 8]);
        ap[1][0] = load8(&PtW[(16 + li) * PTS + quad * 8]);
        ap[1][1] = load8(&PtW[(16 + li) * PTS + 32 + quad * 8]);
        for (int t = 0; t < 4; ++t) {
            bf16x8 bv0 = load8(&Vt[(t * 16 + li) * PS + quad * 8]);
            bf16x8 bv1 = load8(&Vt[(t * 16 + li) * PS + 32 + quad * 8]);
            for (int mt = 0; mt < 2; ++mt) {
                o[mt][t] = MFMA16(ap[mt][0], bv0, o[mt][t]);
                o[mt][t] = MFMA16(ap[mt][1], bv1, o[mt][t]);
            }
        }
        __syncthreads();
    }

    // reduce l across the 16 lanes of each row group
    for (int off = 1; off < 16; off <<= 1)
        for (int mt = 0; mt < 2; ++mt)
            for (int r = 0; r < 4; ++r)
                lsum[mt][r] += __shfl_xor(lsum[mt][r], off);

    // write bf16 partial O (unnormalized) + fp32 l
    bf16* ob = Opart + ((size_t)bx * 128 + wave * 32) * 64;
    for (int mt = 0; mt < 2; ++mt)
        for (int t = 0; t < 4; ++t)
            for (int r = 0; r < 4; ++r)
                ob[(size_t)(mt * 16 + quad * 4 + r) * 64 + t * 16 + li] =
                    __float2bfloat16(o[mt][t][r]);
    if (li == 0)
        for (int mt = 0; mt < 2; ++mt)
            for (int r = 0; r < 4; ++r)
                lpart[(size_t)bx * 128 + wave * 32 + mt * 16 + quad * 4 + r] = lsum[mt][r];
}

// ---------------------------------------------------------------------------
// Combine 4 K-split partials (plain sums). Grid 512 x 256 thr.
// ---------------------------------------------------------------------------
__global__ void attn_combine(const bf16* __restrict__ Opart,
                             const float* __restrict__ lpart,
                             bf16* __restrict__ op) {
    const int gidx = blockIdx.x * 256 + threadIdx.x;  // 0..131071
    const int row  = gidx >> 2;                        // 0..32767 = (b,h,q)
    const int c0   = (gidx & 3) * 16;
    const int b    = row >> 14;
    const int h    = (row >> 11) & 7;
    const int q    = row & 2047;
    const int qt   = q >> 7;
    const int r128 = q & 127;
    const int base = (((b * 8 + h) * 16) + qt) * 4;

    float acc[16];
    for (int j = 0; j < 16; ++j) acc[j] = 0.f;
    float L = 0.f;
    for (int s = 0; s < 4; ++s) {
        const bf16* src = Opart + ((size_t)(base + s) * 128 + r128) * 64 + c0;
        bf16x8 v0 = load8(src);
        bf16x8 v1 = load8(src + 8);
        for (int j = 0; j < 8; ++j) {
            acc[j]     += bfb2f(v0[j]);
            acc[8 + j] += bfb2f(v1[j]);
        }
        L += lpart[(size_t)(base + s) * 128 + r128];
    }
    const float invL = 1.0f / L;

    bf16* dst = op + ((size_t)b * 2048 + q) * 512 + h * 64 + c0;
    bf16x8 o0, o1;
    for (int j = 0; j < 8; ++j) {
        o0[j] = f2bf(acc[j] * invL);
        o1[j] = f2bf(acc[8 + j] * invL);
    }
    *reinterpret_cast<bf16x8*>(dst)     = o0;
    *reinterpret_cast<bf16x8*>(dst + 8) = o1;
}

// ---------------------------------------------------------------------------
extern "C" void kernel_launch(void* const* d_in, const int* in_sizes, int n_in,
                              void* d_out, int out_size, void* d_ws, size_t ws_size,
                              hipStream_t stream) {
    const float* q    = (const float*)d_in[0];
    const float* kv   = (const float*)d_in[1];
    const float* gate = (const float*)d_in[2];
    const int*   mask = (const int*)d_in[3];
    const float* Wq = (const float*)d_in[4];  const float* bq = (const float*)d_in[5];
    const float* Wk = (const float*)d_in[6];  const float* bk = (const float*)d_in[7];
    const float* Wv = (const float*)d_in[8];  const float* bv = (const float*)d_in[9];
    const float* Wo = (const float*)d_in[10]; const float* bo = (const float*)d_in[11];
    float* out = (float*)d_out;

    // workspace (MB offsets): g2@0, Wqb@1, Wkb@1.5, Wvb@2, Wob@2.5, qb@3(4),
    // kvb@7(8), qp@15(4), kp@19(8), vpt@27(8), op@35(4),
    // Opart bf16 @39(16), lpart fp32 @55(0.5)  -> ~56 MB
    char* ws = (char*)d_ws;
    float* g2  = (float*)ws;
    bf16* Wqb  = (bf16*)(ws + (1u  << 20));
    bf16* Wkb  = (bf16*)(ws + (1u  << 20) + (512u << 10));
    bf16* Wvb  = (bf16*)(ws + (2u  << 20));
    bf16* Wob  = (bf16*)(ws + (2u  << 20) + (512u << 10));
    bf16* qb   = (bf16*)(ws + (3u  << 20));
    bf16* kvb  = (bf16*)(ws + (7u  << 20));
    bf16* qp   = (bf16*)(ws + (15u << 20));
    bf16* kp   = (bf16*)(ws + (19u << 20));
    bf16* vpt  = (bf16*)(ws + (27u << 20));
    bf16* op   = (bf16*)(ws + (35u << 20));
    bf16* Opart = (bf16*)(ws + (39u << 20));
    float* lpart = (float*)(ws + (55u << 20));

    prep_all<<<7200, 256, 0, stream>>>(q, kv, Wq, Wk, Wv, Wo, gate, mask,
                                       qb, kvb, Wqb, Wkb, Wvb, Wob, g2);
    proj_qkv<<<dim3(8, 160), 256, 0, stream>>>(qb, kvb, Wqb, bq, Wkb, bk,
                                               Wvb, bv, qp, kp, vpt);
    attn_kernel<<<1024, 256, 0, stream>>>(qp, kp, vpt, g2, Opart, lpart);
    attn_combine<<<512, 256, 0, stream>>>(Opart, lpart, op);
    proj_o<<<dim3(8, 32), 256, 0, stream>>>(op, Wob, bo, out);
}

// Round 8
// 223.097 us; speedup vs baseline: 1.0325x; 1.0148x over previous
//
#include <hip/hip_runtime.h>
#include <hip/hip_bf16.h>

// Problem: B=2, LQ=2048, LK=4096, D_MODEL=512, NHEAD=8, D_HEAD=64
// Inputs fp32 (+ int32 mask). Internal: bf16 MFMA, fp32 accumulation.
// Round 8: attn staging reverted to round-5 direct global->LDS (the r6/r7
// register-prefetch was sunk by the scheduler regardless of launch_bounds —
// compiler-defeats-pipelining, m131/m133 class). Kept: exp2 path, PTS=68,
// bf16 partials. New: P-store bf16 conversion via (bits+0x8000)>>16 (2 VALU
// ops vs ~4 for RNE) — the P-pack was ~250 cyc/iter of pure VALU.

using bf16  = __hip_bfloat16;
using bf16x8 = __attribute__((ext_vector_type(8))) short;  // 8 bf16 = 4 VGPRs
using f32x4  = __attribute__((ext_vector_type(4))) float;

#define MFMA16(a, b, c) __builtin_amdgcn_mfma_f32_16x16x32_bf16((a), (b), (c), 0, 0, 0)

// 0.125 * log2(e): folds the 1/sqrt(64) scale and the exp->exp2 conversion
#define SCALE_LOG2E 0.18033688011112042f

__device__ __forceinline__ bf16x8 load8(const bf16* p) {
    return *reinterpret_cast<const bf16x8*>(p);
}
__device__ __forceinline__ short f2bf(float x) {
    bf16 h = __float2bfloat16(x);
    return *reinterpret_cast<short*>(&h);
}
__device__ __forceinline__ short f2bf_fast(float x) {   // round-half-up
    unsigned u = (__builtin_bit_cast(unsigned, x) + 0x8000u) >> 16;
    return (short)u;
}
__device__ __forceinline__ float bfb2f(short s) {
    unsigned int u = ((unsigned int)(unsigned short)s) << 16;
    return __builtin_bit_cast(float, u);
}

// ---------------------------------------------------------------------------
// One fused prep launch, 7200 blocks:
//   blocks 0..6143   : fp32->bf16 cvt of q (1/3) and kv (2/3), 4 elems/thread
//   blocks 6144..7167: fp32->bf16 cvt of the 4 weight matrices
//   blocks 7168..7199: gate -> g2 = mask ? log2(max(gate,1e-6)) : -1e30
// ---------------------------------------------------------------------------
__global__ void prep_all(const float* __restrict__ q, const float* __restrict__ kv,
                         const float* __restrict__ Wq, const float* __restrict__ Wk,
                         const float* __restrict__ Wv, const float* __restrict__ Wo,
                         const float* __restrict__ gate, const int* __restrict__ mask,
                         bf16* __restrict__ qb, bf16* __restrict__ kvb,
                         bf16* __restrict__ Wqb, bf16* __restrict__ Wkb,
                         bf16* __restrict__ Wvb, bf16* __restrict__ Wob,
                         float* __restrict__ g2) {
    const int bid = blockIdx.x;
    const int tid = threadIdx.x;
    if (bid < 7168) {
        const float* src; bf16* dst; int j;
        if (bid < 6144) {
            int i = bid * 256 + tid;                  // 0..1572863
            if (i < 524288) { src = q;  dst = qb;  j = i; }
            else            { src = kv; dst = kvb; j = i - 524288; }
        } else {
            int i = (bid - 6144) * 256 + tid;         // 0..262143
            int t = i >> 16; j = i & 65535;
            src = (t == 0) ? Wq : (t == 1) ? Wk : (t == 2) ? Wv : Wo;
            dst = (t == 0) ? Wqb : (t == 1) ? Wkb : (t == 2) ? Wvb : Wob;
        }
        float4 v = reinterpret_cast<const float4*>(src)[j];
        ushort4 o;
        o.x = (unsigned short)f2bf(v.x);
        o.y = (unsigned short)f2bf(v.y);
        o.z = (unsigned short)f2bf(v.z);
        o.w = (unsigned short)f2bf(v.w);
        reinterpret_cast<ushort4*>(dst)[j] = o;
    } else {
        int i = (bid - 7168) * 256 + tid;             // 0..8191
        float gv = fmaxf(gate[i], 1e-6f);
        g2[i] = mask[i] ? log2f(gv) : -1e30f;
    }
}

// ---------------------------------------------------------------------------
// Projection body: C = X @ W^T + bias. X:[M,512] bf16, W bf16 row-major
// W[out][in]. Block 256 thr / 4 waves; tile 128 rows x 64 cols; wave 32x64.
// W col-block in LDS, two 256-wide K phases (stride 264, bank-clean).
// mode 0: fp32 row-major [M,512]
// mode 1: bf16 per-head   [(b*8+h)*L + i]*64 + dh
// mode 2: bf16 per-head^T [(b*8+h)*64 + dh]*L + i
// ---------------------------------------------------------------------------
__device__ __forceinline__ void proj_body(const bf16* __restrict__ X,
                                          const bf16* __restrict__ W,
                                          const float* __restrict__ bias,
                                          void* __restrict__ Cout,
                                          int mode, int L, int mb, bf16* Ws) {
    const int tid  = threadIdx.x;
    const int wave = tid >> 6;
    const int lane = tid & 63;
    const int li   = lane & 15;
    const int quad = lane >> 4;
    const int n0   = blockIdx.x * 64;
    const int m0   = mb * 128 + wave * 32;

    f32x4 zero = {0.f, 0.f, 0.f, 0.f};
    f32x4 acc[2][4];
    for (int mt = 0; mt < 2; ++mt)
        for (int t = 0; t < 4; ++t) acc[mt][t] = zero;

    const bf16* x0 = X + (size_t)(m0 + li) * 512;
    const bf16* x1 = X + (size_t)(m0 + 16 + li) * 512;

    for (int p = 0; p < 2; ++p) {
        __syncthreads();
        for (int i = 0; i < 8; ++i) {        // stage 64 x 256 W block
            const int c  = i * 256 + tid;
            const int cr = c >> 5;
            const int kc = (c & 31) * 8;
            *reinterpret_cast<bf16x8*>(&Ws[cr * 264 + kc]) =
                load8(W + (size_t)(n0 + cr) * 512 + p * 256 + kc);
        }
        __syncthreads();

        for (int k0 = 0; k0 < 256; k0 += 32) {
            bf16x8 a0 = load8(x0 + p * 256 + k0 + quad * 8);
            bf16x8 a1 = load8(x1 + p * 256 + k0 + quad * 8);
            for (int t = 0; t < 4; ++t) {
                bf16x8 w8 = load8(&Ws[(t * 16 + li) * 264 + k0 + quad * 8]);
                acc[0][t] = MFMA16(a0, w8, acc[0][t]);
                acc[1][t] = MFMA16(a1, w8, acc[1][t]);
            }
        }
    }

    for (int t = 0; t < 4; ++t) {
        const int col = n0 + t * 16 + li;
        const float bcol = bias[col];
        for (int mt = 0; mt < 2; ++mt) {
            for (int r = 0; r < 4; ++r) {
                const int row = m0 + mt * 16 + quad * 4 + r;   // C-layout
                const float v = acc[mt][t][r] + bcol;
                if (mode == 0) {
                    ((float*)Cout)[(size_t)row * 512 + col] = v;
                } else {
                    const int bb2 = row / L;
                    const int i   = row - bb2 * L;
                    const int hh  = col >> 6;
                    const int dh  = col & 63;
                    size_t idx;
                    if (mode == 1) idx = ((size_t)(bb2 * 8 + hh) * L + i) * 64 + dh;
                    else           idx = ((size_t)(bb2 * 8 + hh) * 64 + dh) * L + i;
                    ((bf16*)Cout)[idx] = __float2bfloat16(v);
                }
            }
        }
    }
}

// Fused Q/K/V projections: grid (8, 160). y<32: Q; y<96: K; else V.
__global__ void __launch_bounds__(256, 4)
proj_qkv(const bf16* __restrict__ qb, const bf16* __restrict__ kvb,
         const bf16* __restrict__ Wq, const float* __restrict__ bq,
         const bf16* __restrict__ Wk, const float* __restrict__ bk,
         const bf16* __restrict__ Wv, const float* __restrict__ bv,
         bf16* __restrict__ qp, bf16* __restrict__ kp,
         bf16* __restrict__ vpt) {
    __shared__ alignas(16) bf16 Ws[64 * 264];
    const int my = blockIdx.y;
    if (my < 32)      proj_body(qb,  Wq, bq, qp,  1, 2048, my,      Ws);
    else if (my < 96) proj_body(kvb, Wk, bk, kp,  1, 4096, my - 32, Ws);
    else              proj_body(kvb, Wv, bv, vpt, 2, 4096, my - 96, Ws);
}

// Output projection: grid (8, 32), fp32 out.
__global__ void __launch_bounds__(256, 4)
proj_o(const bf16* __restrict__ op, const bf16* __restrict__ Wo,
       const float* __restrict__ bo, float* __restrict__ out) {
    __shared__ alignas(16) bf16 Ws[64 * 264];
    proj_body(op, Wo, bo, out, 0, 1, blockIdx.y, Ws);
}

// ---------------------------------------------------------------------------
// K-split flash attention, no max-subtraction, exp2 path, direct global->LDS
// staging (r5 structure). Grid: 1024 = b(2) x h(8) x qtile(16) x ks(4).
// Block: 256 thr = 4 waves; wave owns 32 Q-rows. Writes UNNORMALIZED bf16
// partial O + fp32 l.
// ---------------------------------------------------------------------------
#define PS  72   // K/V tile stride
#define PTS 68   // P tile stride
__global__ void attn_kernel(const bf16* __restrict__ qp, const bf16* __restrict__ kp,
                            const bf16* __restrict__ vpt, const float* __restrict__ g2,
                            bf16* __restrict__ Opart, float* __restrict__ lpart) {
    __shared__ alignas(16) bf16 Kt[64 * PS];
    __shared__ alignas(16) bf16 Vt[64 * PS];
    __shared__ alignas(16) short Pt[4 * 32 * PTS];
    __shared__ float gs[64];

    const int tid  = threadIdx.x;
    const int wave = tid >> 6;
    const int lane = tid & 63;
    const int li   = lane & 15;
    const int quad = lane >> 4;

    const int bx = blockIdx.x;          // b*512 + h*64 + qt*4 + ks
    const int ks = bx & 3;
    const int qt = (bx >> 2) & 15;
    const int h  = (bx >> 6) & 7;
    const int b  = bx >> 9;
    const size_t bh = (size_t)(b * 8 + h);

    // Q fragments: 2 m-subtiles x 2 k-halves
    const bf16* qb0 = qp + (bh * 2048 + (size_t)qt * 128 + wave * 32 + li) * 64;
    bf16x8 aq[2][2];
    aq[0][0] = load8(qb0 + quad * 8);
    aq[0][1] = load8(qb0 + 32 + quad * 8);
    aq[1][0] = load8(qb0 + 16 * 64 + quad * 8);
    aq[1][1] = load8(qb0 + 16 * 64 + 32 + quad * 8);

    f32x4 zero = {0.f, 0.f, 0.f, 0.f};
    f32x4 o[2][4];
    for (int mt = 0; mt < 2; ++mt)
        for (int t = 0; t < 4; ++t) o[mt][t] = zero;
    float lsum[2][4] = {{0.f, 0.f, 0.f, 0.f}, {0.f, 0.f, 0.f, 0.f}};

    const bf16* ksrc  = kp  + bh * 4096 * 64;
    const bf16* vsrc  = vpt + bh * 64 * 4096;
    const float* gsrc = g2 + (size_t)b * 4096;

    short* PtW = &Pt[wave * 32 * PTS];
    const int r0 = tid >> 3;
    const int cg = (tid & 7) * 8;

    for (int kt = ks * 16; kt < ks * 16 + 16; ++kt) {
        {   // stage K tile and V^T tile (direct: compiler orders vm->ds)
            const bf16* kst = ksrc + (size_t)kt * 4096;
            *reinterpret_cast<bf16x8*>(&Kt[r0 * PS + cg])        = load8(kst + r0 * 64 + cg);
            *reinterpret_cast<bf16x8*>(&Kt[(r0 + 32) * PS + cg]) = load8(kst + (r0 + 32) * 64 + cg);
            const bf16* vs = vsrc + kt * 64;
            *reinterpret_cast<bf16x8*>(&Vt[r0 * PS + cg])        = load8(vs + (size_t)r0 * 4096 + cg);
            *reinterpret_cast<bf16x8*>(&Vt[(r0 + 32) * PS + cg]) = load8(vs + (size_t)(r0 + 32) * 4096 + cg);
            if (tid < 64) gs[tid] = gsrc[kt * 64 + tid];
        }
        __syncthreads();

        // S (32 x 64) = Q @ K_tile^T, then P = exp2(S*SCALE_LOG2E + g2)
        for (int t = 0; t < 4; ++t) {
            bf16x8 bk0 = load8(&Kt[(t * 16 + li) * PS + quad * 8]);
            bf16x8 bk1 = load8(&Kt[(t * 16 + li) * PS + 32 + quad * 8]);
            const float gv = gs[t * 16 + li];
            for (int mt = 0; mt < 2; ++mt) {
                f32x4 acc = zero;
                acc = MFMA16(aq[mt][0], bk0, acc);
                acc = MFMA16(aq[mt][1], bk1, acc);
                for (int r = 0; r < 4; ++r) {
                    const float p = exp2f(fmaf(acc[r], SCALE_LOG2E, gv));
                    lsum[mt][r] += p;
                    PtW[(mt * 16 + quad * 4 + r) * PTS + t * 16 + li] = f2bf_fast(p);
                }
            }
        }

        // O += P @ V_tile
        bf16x8 ap[2][2];
        ap[0][0] = *reinterpret_cast<bf16x8*>(&PtW[li * PTS + quad * 8]);
        ap[0][1] = *reinterpret_cast<bf16x8*>(&PtW[li * PTS + 32 + quad * 8]);
        ap[1][0] = *reinterpret_cast<bf16x8*>(&PtW[(16 + li) * PTS + quad * 8]);
        ap[1][1] = *reinterpret_cast<bf16x8*>(&PtW[(16 + li) * PTS + 32 + quad * 8]);
        for (int t = 0; t < 4; ++t) {
            bf16x8 bv0 = load8(&Vt[(t * 16 + li) * PS + quad * 8]);
            bf16x8 bv1 = load8(&Vt[(t * 16 + li) * PS + 32 + quad * 8]);
            for (int mt = 0; mt < 2; ++mt) {
                o[mt][t] = MFMA16(ap[mt][0], bv0, o[mt][t]);
                o[mt][t] = MFMA16(ap[mt][1], bv1, o[mt][t]);
            }
        }
        __syncthreads();
    }

    // reduce l across the 16 lanes of each row group
    for (int off = 1; off < 16; off <<= 1)
        for (int mt = 0; mt < 2; ++mt)
            for (int r = 0; r < 4; ++r)
                lsum[mt][r] += __shfl_xor(lsum[mt][r], off);

    // write bf16 partial O (unnormalized) + fp32 l
    bf16* ob = Opart + ((size_t)bx * 128 + wave * 32) * 64;
    for (int mt = 0; mt < 2; ++mt)
        for (int t = 0; t < 4; ++t)
            for (int r = 0; r < 4; ++r)
                ob[(size_t)(mt * 16 + quad * 4 + r) * 64 + t * 16 + li] =
                    __float2bfloat16(o[mt][t][r]);
    if (li == 0)
        for (int mt = 0; mt < 2; ++mt)
            for (int r = 0; r < 4; ++r)
                lpart[(size_t)bx * 128 + wave * 32 + mt * 16 + quad * 4 + r] = lsum[mt][r];
}

// ---------------------------------------------------------------------------
// Combine 4 K-split partials (plain sums). Grid 512 x 256 thr.
// ---------------------------------------------------------------------------
__global__ void attn_combine(const bf16* __restrict__ Opart,
                             const float* __restrict__ lpart,
                             bf16* __restrict__ op) {
    const int gidx = blockIdx.x * 256 + threadIdx.x;  // 0..131071
    const int row  = gidx >> 2;                        // 0..32767 = (b,h,q)
    const int c0   = (gidx & 3) * 16;
    const int b    = row >> 14;
    const int h    = (row >> 11) & 7;
    const int q    = row & 2047;
    const int qt   = q >> 7;
    const int r128 = q & 127;
    const int base = (((b * 8 + h) * 16) + qt) * 4;

    float acc[16];
    for (int j = 0; j < 16; ++j) acc[j] = 0.f;
    float L = 0.f;
    for (int s = 0; s < 4; ++s) {
        const bf16* src = Opart + ((size_t)(base + s) * 128 + r128) * 64 + c0;
        bf16x8 v0 = load8(src);
        bf16x8 v1 = load8(src + 8);
        for (int j = 0; j < 8; ++j) {
            acc[j]     += bfb2f(v0[j]);
            acc[8 + j] += bfb2f(v1[j]);
        }
        L += lpart[(size_t)(base + s) * 128 + r128];
    }
    const float invL = 1.0f / L;

    bf16* dst = op + ((size_t)b * 2048 + q) * 512 + h * 64 + c0;
    bf16x8 o0, o1;
    for (int j = 0; j < 8; ++j) {
        o0[j] = f2bf(acc[j] * invL);
        o1[j] = f2bf(acc[8 + j] * invL);
    }
    *reinterpret_cast<bf16x8*>(dst)     = o0;
    *reinterpret_cast<bf16x8*>(dst + 8) = o1;
}

// ---------------------------------------------------------------------------
extern "C" void kernel_launch(void* const* d_in, const int* in_sizes, int n_in,
                              void* d_out, int out_size, void* d_ws, size_t ws_size,
                              hipStream_t stream) {
    const float* q    = (const float*)d_in[0];
    const float* kv   = (const float*)d_in[1];
    const float* gate = (const float*)d_in[2];
    const int*   mask = (const int*)d_in[3];
    const float* Wq = (const float*)d_in[4];  const float* bq = (const float*)d_in[5];
    const float* Wk = (const float*)d_in[6];  const float* bk = (const float*)d_in[7];
    const float* Wv = (const float*)d_in[8];  const float* bv = (const float*)d_in[9];
    const float* Wo = (const float*)d_in[10]; const float* bo = (const float*)d_in[11];
    float* out = (float*)d_out;

    // workspace (MB offsets): g2@0, Wqb@1, Wkb@1.5, Wvb@2, Wob@2.5, qb@3(4),
    // kvb@7(8), qp@15(4), kp@19(8), vpt@27(8), op@35(4),
    // Opart bf16 @39(16), lpart fp32 @55(0.5)  -> ~56 MB
    char* ws = (char*)d_ws;
    float* g2  = (float*)ws;
    bf16* Wqb  = (bf16*)(ws + (1u  << 20));
    bf16* Wkb  = (bf16*)(ws + (1u  << 20) + (512u << 10));
    bf16* Wvb  = (bf16*)(ws + (2u  << 20));
    bf16* Wob  = (bf16*)(ws + (2u  << 20) + (512u << 10));
    bf16* qb   = (bf16*)(ws + (3u  << 20));
    bf16* kvb  = (bf16*)(ws + (7u  << 20));
    bf16* qp   = (bf16*)(ws + (15u << 20));
    bf16* kp   = (bf16*)(ws + (19u << 20));
    bf16* vpt  = (bf16*)(ws + (27u << 20));
    bf16* op   = (bf16*)(ws + (35u << 20));
    bf16* Opart = (bf16*)(ws + (39u << 20));
    float* lpart = (float*)(ws + (55u << 20));

    prep_all<<<7200, 256, 0, stream>>>(q, kv, Wq, Wk, Wv, Wo, gate, mask,
                                       qb, kvb, Wqb, Wkb, Wvb, Wob, g2);
    proj_qkv<<<dim3(8, 160), 256, 0, stream>>>(qb, kvb, Wqb, bq, Wkb, bk,
                                               Wvb, bv, qp, kp, vpt);
    attn_kernel<<<1024, 256, 0, stream>>>(qp, kp, vpt, g2, Opart, lpart);
    attn_combine<<<512, 256, 0, stream>>>(Opart, lpart, op);
    proj_o<<<dim3(8, 32), 256, 0, stream>>>(op, Wob, bo, out);
}

// Round 9
// 217.628 us; speedup vs baseline: 1.0585x; 1.0251x over previous
//
#include <hip/hip_runtime.h>
#include <hip/hip_bf16.h>

// Problem: B=2, LQ=2048, LK=4096, D_MODEL=512, NHEAD=8, D_HEAD=64
// Inputs fp32 (+ int32 mask). Internal: bf16 MFMA, fp32 accumulation.
// Round 9: r8 with exp2f -> __builtin_amdgcn_exp2f (raw v_exp_f32).
// r6-r8 forensics: libm exp2f lowered to precise OCML exp2 (+~10 VALU
// ops/call denormal guard) = +14us of VALU vs r5's __expf. The r6 prefetch
// was ~neutral; the exp was the regression. Builtin exp2 is the fix that
// keeps the folded 0.125*log2e scale.

using bf16  = __hip_bfloat16;
using bf16x8 = __attribute__((ext_vector_type(8))) short;  // 8 bf16 = 4 VGPRs
using f32x4  = __attribute__((ext_vector_type(4))) float;

#define MFMA16(a, b, c) __builtin_amdgcn_mfma_f32_16x16x32_bf16((a), (b), (c), 0, 0, 0)

// 0.125 * log2(e): folds the 1/sqrt(64) scale and the exp->exp2 conversion
#define SCALE_LOG2E 0.18033688011112042f

__device__ __forceinline__ bf16x8 load8(const bf16* p) {
    return *reinterpret_cast<const bf16x8*>(p);
}
__device__ __forceinline__ short f2bf(float x) {
    bf16 h = __float2bfloat16(x);
    return *reinterpret_cast<short*>(&h);
}
__device__ __forceinline__ short f2bf_fast(float x) {   // round-half-up
    unsigned u = (__builtin_bit_cast(unsigned, x) + 0x8000u) >> 16;
    return (short)u;
}
__device__ __forceinline__ float bfb2f(short s) {
    unsigned int u = ((unsigned int)(unsigned short)s) << 16;
    return __builtin_bit_cast(float, u);
}

// ---------------------------------------------------------------------------
// One fused prep launch, 7200 blocks:
//   blocks 0..6143   : fp32->bf16 cvt of q (1/3) and kv (2/3), 4 elems/thread
//   blocks 6144..7167: fp32->bf16 cvt of the 4 weight matrices
//   blocks 7168..7199: gate -> g2 = mask ? log2(max(gate,1e-6)) : -1e30
// ---------------------------------------------------------------------------
__global__ void prep_all(const float* __restrict__ q, const float* __restrict__ kv,
                         const float* __restrict__ Wq, const float* __restrict__ Wk,
                         const float* __restrict__ Wv, const float* __restrict__ Wo,
                         const float* __restrict__ gate, const int* __restrict__ mask,
                         bf16* __restrict__ qb, bf16* __restrict__ kvb,
                         bf16* __restrict__ Wqb, bf16* __restrict__ Wkb,
                         bf16* __restrict__ Wvb, bf16* __restrict__ Wob,
                         float* __restrict__ g2) {
    const int bid = blockIdx.x;
    const int tid = threadIdx.x;
    if (bid < 7168) {
        const float* src; bf16* dst; int j;
        if (bid < 6144) {
            int i = bid * 256 + tid;                  // 0..1572863
            if (i < 524288) { src = q;  dst = qb;  j = i; }
            else            { src = kv; dst = kvb; j = i - 524288; }
        } else {
            int i = (bid - 6144) * 256 + tid;         // 0..262143
            int t = i >> 16; j = i & 65535;
            src = (t == 0) ? Wq : (t == 1) ? Wk : (t == 2) ? Wv : Wo;
            dst = (t == 0) ? Wqb : (t == 1) ? Wkb : (t == 2) ? Wvb : Wob;
        }
        float4 v = reinterpret_cast<const float4*>(src)[j];
        ushort4 o;
        o.x = (unsigned short)f2bf(v.x);
        o.y = (unsigned short)f2bf(v.y);
        o.z = (unsigned short)f2bf(v.z);
        o.w = (unsigned short)f2bf(v.w);
        reinterpret_cast<ushort4*>(dst)[j] = o;
    } else {
        int i = (bid - 7168) * 256 + tid;             // 0..8191
        float gv = fmaxf(gate[i], 1e-6f);
        g2[i] = mask[i] ? log2f(gv) : -1e30f;
    }
}

// ---------------------------------------------------------------------------
// Projection body: C = X @ W^T + bias. X:[M,512] bf16, W bf16 row-major
// W[out][in]. Block 256 thr / 4 waves; tile 128 rows x 64 cols; wave 32x64.
// W col-block in LDS, two 256-wide K phases (stride 264, bank-clean).
// mode 0: fp32 row-major [M,512]
// mode 1: bf16 per-head   [(b*8+h)*L + i]*64 + dh
// mode 2: bf16 per-head^T [(b*8+h)*64 + dh]*L + i
// ---------------------------------------------------------------------------
__device__ __forceinline__ void proj_body(const bf16* __restrict__ X,
                                          const bf16* __restrict__ W,
                                          const float* __restrict__ bias,
                                          void* __restrict__ Cout,
                                          int mode, int L, int mb, bf16* Ws) {
    const int tid  = threadIdx.x;
    const int wave = tid >> 6;
    const int lane = tid & 63;
    const int li   = lane & 15;
    const int quad = lane >> 4;
    const int n0   = blockIdx.x * 64;
    const int m0   = mb * 128 + wave * 32;

    f32x4 zero = {0.f, 0.f, 0.f, 0.f};
    f32x4 acc[2][4];
    for (int mt = 0; mt < 2; ++mt)
        for (int t = 0; t < 4; ++t) acc[mt][t] = zero;

    const bf16* x0 = X + (size_t)(m0 + li) * 512;
    const bf16* x1 = X + (size_t)(m0 + 16 + li) * 512;

    for (int p = 0; p < 2; ++p) {
        __syncthreads();
        for (int i = 0; i < 8; ++i) {        // stage 64 x 256 W block
            const int c  = i * 256 + tid;
            const int cr = c >> 5;
            const int kc = (c & 31) * 8;
            *reinterpret_cast<bf16x8*>(&Ws[cr * 264 + kc]) =
                load8(W + (size_t)(n0 + cr) * 512 + p * 256 + kc);
        }
        __syncthreads();

        for (int k0 = 0; k0 < 256; k0 += 32) {
            bf16x8 a0 = load8(x0 + p * 256 + k0 + quad * 8);
            bf16x8 a1 = load8(x1 + p * 256 + k0 + quad * 8);
            for (int t = 0; t < 4; ++t) {
                bf16x8 w8 = load8(&Ws[(t * 16 + li) * 264 + k0 + quad * 8]);
                acc[0][t] = MFMA16(a0, w8, acc[0][t]);
                acc[1][t] = MFMA16(a1, w8, acc[1][t]);
            }
        }
    }

    for (int t = 0; t < 4; ++t) {
        const int col = n0 + t * 16 + li;
        const float bcol = bias[col];
        for (int mt = 0; mt < 2; ++mt) {
            for (int r = 0; r < 4; ++r) {
                const int row = m0 + mt * 16 + quad * 4 + r;   // C-layout
                const float v = acc[mt][t][r] + bcol;
                if (mode == 0) {
                    ((float*)Cout)[(size_t)row * 512 + col] = v;
                } else {
                    const int bb2 = row / L;
                    const int i   = row - bb2 * L;
                    const int hh  = col >> 6;
                    const int dh  = col & 63;
                    size_t idx;
                    if (mode == 1) idx = ((size_t)(bb2 * 8 + hh) * L + i) * 64 + dh;
                    else           idx = ((size_t)(bb2 * 8 + hh) * 64 + dh) * L + i;
                    ((bf16*)Cout)[idx] = __float2bfloat16(v);
                }
            }
        }
    }
}

// Fused Q/K/V projections: grid (8, 160). y<32: Q; y<96: K; else V.
__global__ void __launch_bounds__(256, 4)
proj_qkv(const bf16* __restrict__ qb, const bf16* __restrict__ kvb,
         const bf16* __restrict__ Wq, const float* __restrict__ bq,
         const bf16* __restrict__ Wk, const float* __restrict__ bk,
         const bf16* __restrict__ Wv, const float* __restrict__ bv,
         bf16* __restrict__ qp, bf16* __restrict__ kp,
         bf16* __restrict__ vpt) {
    __shared__ alignas(16) bf16 Ws[64 * 264];
    const int my = blockIdx.y;
    if (my < 32)      proj_body(qb,  Wq, bq, qp,  1, 2048, my,      Ws);
    else if (my < 96) proj_body(kvb, Wk, bk, kp,  1, 4096, my - 32, Ws);
    else              proj_body(kvb, Wv, bv, vpt, 2, 4096, my - 96, Ws);
}

// Output projection: grid (8, 32), fp32 out.
__global__ void __launch_bounds__(256, 4)
proj_o(const bf16* __restrict__ op, const bf16* __restrict__ Wo,
       const float* __restrict__ bo, float* __restrict__ out) {
    __shared__ alignas(16) bf16 Ws[64 * 264];
    proj_body(op, Wo, bo, out, 0, 1, blockIdx.y, Ws);
}

// ---------------------------------------------------------------------------
// K-split flash attention, no max-subtraction, builtin exp2 (v_exp_f32),
// direct global->LDS staging. Grid: 1024 = b(2) x h(8) x qtile(16) x ks(4).
// Block: 256 thr = 4 waves; wave owns 32 Q-rows. Writes UNNORMALIZED bf16
// partial O + fp32 l.
// ---------------------------------------------------------------------------
#define PS  72   // K/V tile stride
#define PTS 68   // P tile stride
__global__ void attn_kernel(const bf16* __restrict__ qp, const bf16* __restrict__ kp,
                            const bf16* __restrict__ vpt, const float* __restrict__ g2,
                            bf16* __restrict__ Opart, float* __restrict__ lpart) {
    __shared__ alignas(16) bf16 Kt[64 * PS];
    __shared__ alignas(16) bf16 Vt[64 * PS];
    __shared__ alignas(16) short Pt[4 * 32 * PTS];
    __shared__ float gs[64];

    const int tid  = threadIdx.x;
    const int wave = tid >> 6;
    const int lane = tid & 63;
    const int li   = lane & 15;
    const int quad = lane >> 4;

    const int bx = blockIdx.x;          // b*512 + h*64 + qt*4 + ks
    const int ks = bx & 3;
    const int qt = (bx >> 2) & 15;
    const int h  = (bx >> 6) & 7;
    const int b  = bx >> 9;
    const size_t bh = (size_t)(b * 8 + h);

    // Q fragments: 2 m-subtiles x 2 k-halves
    const bf16* qb0 = qp + (bh * 2048 + (size_t)qt * 128 + wave * 32 + li) * 64;
    bf16x8 aq[2][2];
    aq[0][0] = load8(qb0 + quad * 8);
    aq[0][1] = load8(qb0 + 32 + quad * 8);
    aq[1][0] = load8(qb0 + 16 * 64 + quad * 8);
    aq[1][1] = load8(qb0 + 16 * 64 + 32 + quad * 8);

    f32x4 zero = {0.f, 0.f, 0.f, 0.f};
    f32x4 o[2][4];
    for (int mt = 0; mt < 2; ++mt)
        for (int t = 0; t < 4; ++t) o[mt][t] = zero;
    float lsum[2][4] = {{0.f, 0.f, 0.f, 0.f}, {0.f, 0.f, 0.f, 0.f}};

    const bf16* ksrc  = kp  + bh * 4096 * 64;
    const bf16* vsrc  = vpt + bh * 64 * 4096;
    const float* gsrc = g2 + (size_t)b * 4096;

    short* PtW = &Pt[wave * 32 * PTS];
    const int r0 = tid >> 3;
    const int cg = (tid & 7) * 8;

    for (int kt = ks * 16; kt < ks * 16 + 16; ++kt) {
        {   // stage K tile and V^T tile (direct: compiler orders vm->ds)
            const bf16* kst = ksrc + (size_t)kt * 4096;
            *reinterpret_cast<bf16x8*>(&Kt[r0 * PS + cg])        = load8(kst + r0 * 64 + cg);
            *reinterpret_cast<bf16x8*>(&Kt[(r0 + 32) * PS + cg]) = load8(kst + (r0 + 32) * 64 + cg);
            const bf16* vs = vsrc + kt * 64;
            *reinterpret_cast<bf16x8*>(&Vt[r0 * PS + cg])        = load8(vs + (size_t)r0 * 4096 + cg);
            *reinterpret_cast<bf16x8*>(&Vt[(r0 + 32) * PS + cg]) = load8(vs + (size_t)(r0 + 32) * 4096 + cg);
            if (tid < 64) gs[tid] = gsrc[kt * 64 + tid];
        }
        __syncthreads();

        // S (32 x 64) = Q @ K_tile^T, then P = exp2(S*SCALE_LOG2E + g2)
        for (int t = 0; t < 4; ++t) {
            bf16x8 bk0 = load8(&Kt[(t * 16 + li) * PS + quad * 8]);
            bf16x8 bk1 = load8(&Kt[(t * 16 + li) * PS + 32 + quad * 8]);
            const float gv = gs[t * 16 + li];
            for (int mt = 0; mt < 2; ++mt) {
                f32x4 acc = zero;
                acc = MFMA16(aq[mt][0], bk0, acc);
                acc = MFMA16(aq[mt][1], bk1, acc);
                for (int r = 0; r < 4; ++r) {
                    const float p = __builtin_amdgcn_exp2f(fmaf(acc[r], SCALE_LOG2E, gv));
                    lsum[mt][r] += p;
                    PtW[(mt * 16 + quad * 4 + r) * PTS + t * 16 + li] = f2bf_fast(p);
                }
            }
        }

        // O += P @ V_tile
        bf16x8 ap[2][2];
        ap[0][0] = *reinterpret_cast<bf16x8*>(&PtW[li * PTS + quad * 8]);
        ap[0][1] = *reinterpret_cast<bf16x8*>(&PtW[li * PTS + 32 + quad * 8]);
        ap[1][0] = *reinterpret_cast<bf16x8*>(&PtW[(16 + li) * PTS + quad * 8]);
        ap[1][1] = *reinterpret_cast<bf16x8*>(&PtW[(16 + li) * PTS + 32 + quad * 8]);
        for (int t = 0; t < 4; ++t) {
            bf16x8 bv0 = load8(&Vt[(t * 16 + li) * PS + quad * 8]);
            bf16x8 bv1 = load8(&Vt[(t * 16 + li) * PS + 32 + quad * 8]);
            for (int mt = 0; mt < 2; ++mt) {
                o[mt][t] = MFMA16(ap[mt][0], bv0, o[mt][t]);
                o[mt][t] = MFMA16(ap[mt][1], bv1, o[mt][t]);
            }
        }
        __syncthreads();
    }

    // reduce l across the 16 lanes of each row group
    for (int off = 1; off < 16; off <<= 1)
        for (int mt = 0; mt < 2; ++mt)
            for (int r = 0; r < 4; ++r)
                lsum[mt][r] += __shfl_xor(lsum[mt][r], off);

    // write bf16 partial O (unnormalized) + fp32 l
    bf16* ob = Opart + ((size_t)bx * 128 + wave * 32) * 64;
    for (int mt = 0; mt < 2; ++mt)
        for (int t = 0; t < 4; ++t)
            for (int r = 0; r < 4; ++r)
                ob[(size_t)(mt * 16 + quad * 4 + r) * 64 + t * 16 + li] =
                    __float2bfloat16(o[mt][t][r]);
    if (li == 0)
        for (int mt = 0; mt < 2; ++mt)
            for (int r = 0; r < 4; ++r)
                lpart[(size_t)bx * 128 + wave * 32 + mt * 16 + quad * 4 + r] = lsum[mt][r];
}

// ---------------------------------------------------------------------------
// Combine 4 K-split partials (plain sums). Grid 512 x 256 thr.
// ---------------------------------------------------------------------------
__global__ void attn_combine(const bf16* __restrict__ Opart,
                             const float* __restrict__ lpart,
                             bf16* __restrict__ op) {
    const int gidx = blockIdx.x * 256 + threadIdx.x;  // 0..131071
    const int row  = gidx >> 2;                        // 0..32767 = (b,h,q)
    const int c0   = (gidx & 3) * 16;
    const int b    = row >> 14;
    const int h    = (row >> 11) & 7;
    const int q    = row & 2047;
    const int qt   = q >> 7;
    const int r128 = q & 127;
    const int base = (((b * 8 + h) * 16) + qt) * 4;

    float acc[16];
    for (int j = 0; j < 16; ++j) acc[j] = 0.f;
    float L = 0.f;
    for (int s = 0; s < 4; ++s) {
        const bf16* src = Opart + ((size_t)(base + s) * 128 + r128) * 64 + c0;
        bf16x8 v0 = load8(src);
        bf16x8 v1 = load8(src + 8);
        for (int j = 0; j < 8; ++j) {
            acc[j]     += bfb2f(v0[j]);
            acc[8 + j] += bfb2f(v1[j]);
        }
        L += lpart[(size_t)(base + s) * 128 + r128];
    }
    const float invL = 1.0f / L;

    bf16* dst = op + ((size_t)b * 2048 + q) * 512 + h * 64 + c0;
    bf16x8 o0, o1;
    for (int j = 0; j < 8; ++j) {
        o0[j] = f2bf(acc[j] * invL);
        o1[j] = f2bf(acc[8 + j] * invL);
    }
    *reinterpret_cast<bf16x8*>(dst)     = o0;
    *reinterpret_cast<bf16x8*>(dst + 8) = o1;
}

// ---------------------------------------------------------------------------
extern "C" void kernel_launch(void* const* d_in, const int* in_sizes, int n_in,
                              void* d_out, int out_size, void* d_ws, size_t ws_size,
                              hipStream_t stream) {
    const float* q    = (const float*)d_in[0];
    const float* kv   = (const float*)d_in[1];
    const float* gate = (const float*)d_in[2];
    const int*   mask = (const int*)d_in[3];
    const float* Wq = (const float*)d_in[4];  const float* bq = (const float*)d_in[5];
    const float* Wk = (const float*)d_in[6];  const float* bk = (const float*)d_in[7];
    const float* Wv = (const float*)d_in[8];  const float* bv = (const float*)d_in[9];
    const float* Wo = (const float*)d_in[10]; const float* bo = (const float*)d_in[11];
    float* out = (float*)d_out;

    // workspace (MB offsets): g2@0, Wqb@1, Wkb@1.5, Wvb@2, Wob@2.5, qb@3(4),
    // kvb@7(8), qp@15(4), kp@19(8), vpt@27(8), op@35(4),
    // Opart bf16 @39(16), lpart fp32 @55(0.5)  -> ~56 MB
    char* ws = (char*)d_ws;
    float* g2  = (float*)ws;
    bf16* Wqb  = (bf16*)(ws + (1u  << 20));
    bf16* Wkb  = (bf16*)(ws + (1u  << 20) + (512u << 10));
    bf16* Wvb  = (bf16*)(ws + (2u  << 20));
    bf16* Wob  = (bf16*)(ws + (2u  << 20) + (512u << 10));
    bf16* qb   = (bf16*)(ws + (3u  << 20));
    bf16* kvb  = (bf16*)(ws + (7u  << 20));
    bf16* qp   = (bf16*)(ws + (15u << 20));
    bf16* kp   = (bf16*)(ws + (19u << 20));
    bf16* vpt  = (bf16*)(ws + (27u << 20));
    bf16* op   = (bf16*)(ws + (35u << 20));
    bf16* Opart = (bf16*)(ws + (39u << 20));
    float* lpart = (float*)(ws + (55u << 20));

    prep_all<<<7200, 256, 0, stream>>>(q, kv, Wq, Wk, Wv, Wo, gate, mask,
                                       qb, kvb, Wqb, Wkb, Wvb, Wob, g2);
    proj_qkv<<<dim3(8, 160), 256, 0, stream>>>(qb, kvb, Wqb, bq, Wkb, bk,
                                               Wvb, bv, qp, kp, vpt);
    attn_kernel<<<1024, 256, 0, stream>>>(qp, kp, vpt, g2, Opart, lpart);
    attn_combine<<<512, 256, 0, stream>>>(Opart, lpart, op);
    proj_o<<<dim3(8, 32), 256, 0, stream>>>(op, Wob, bo, out);
}